// Round 17
// baseline (191.524 us; speedup 1.0000x reference)
//
#include <hip/hip_runtime.h>
#include <stdint.h>

typedef unsigned short u16;
typedef __attribute__((ext_vector_type(8))) short bf16x8;
typedef __attribute__((ext_vector_type(4))) float f32x4;
typedef __attribute__((ext_vector_type(4))) uint32_t u32x4;

#define MFMA16(a,b,c) __builtin_amdgcn_mfma_f32_16x16x32_bf16(a,b,c,0,0,0)

__device__ __forceinline__ float bf2f(u16 u){
  union { float f; uint32_t i; } c; c.i = ((uint32_t)u)<<16; return c.f;
}
__device__ __forceinline__ u16 f2bf(float f){
  union { float f; uint32_t i; } c; c.f = f;
  uint32_t r = c.i + 0x7FFFu + ((c.i>>16)&1u);
  return (u16)(r>>16);
}
// asm cvt_pk verified safe at ~100 VGPR (R5/R8/R9); banned >150 VGPR (R10)
__device__ __forceinline__ uint32_t cvt_pk_bf16(float a, float b){
  uint32_t r;
  asm("v_cvt_pk_bf16_f32 %0, %1, %2" : "=v"(r) : "v"(a), "v"(b));
  return r;  // lo = bf16(a), hi = bf16(b)
}

// ---------------- convert x (fp32 -> bf16) ----------------
__global__ void cvt_x_kernel(const float* __restrict__ x, u16* __restrict__ xbf){
  int i = blockIdx.x*256 + threadIdx.x;
  float4 v = ((const float4* __restrict__)x)[i];
  uint2 pk;
  pk.x = (uint32_t)f2bf(v.x) | ((uint32_t)f2bf(v.y)<<16);
  pk.y = (uint32_t)f2bf(v.z) | ((uint32_t)f2bf(v.w)<<16);
  ((uint2*)xbf)[i] = pk;
}

// ------------- transpose + convert weights: W[k][n] -> Wt[n][k] bf16 -------------
__global__ void cvt_w_kernel(const float* __restrict__ Wq, const float* __restrict__ Wk,
                             const float* __restrict__ Wv, const float* __restrict__ Wo,
                             u16* __restrict__ wt, u16* __restrict__ wot){
  __shared__ float t[32][33];
  int w = blockIdx.z;
  const float* W = (w==0)?Wq:(w==1)?Wk:(w==2)?Wv:Wo;
  u16* dst = (w<3) ? (wt + (size_t)w*640*640) : wot;
  int k0 = blockIdx.x*32, n0 = blockIdx.y*32;
  int tx = threadIdx.x, ty = threadIdx.y;
  for (int j=ty; j<32; j+=8) t[j][tx] = W[(size_t)(k0+j)*640 + n0+tx];
  __syncthreads();
  for (int j=ty; j<32; j+=8) dst[(size_t)(n0+j)*640 + k0+tx] = f2bf(t[tx][j]);
}

// ---------------- GEMM: C[12288x640] = A[12288x640] * Bt^T, bf16 MFMA ----------------
// MODE 0: w=0/1 -> Q/K head-major [b][h][s][80]; w=2 -> V^T [b][h][d 80][1024]
//         (V^T written via LDS transpose: coalesced 128B runs along s)
// MODE 1: fp32 out = acc + bias, row-major [m][640]
template<int MODE>
__global__ __launch_bounds__(256,2) void gemm_kernel(
    const u16* __restrict__ A, const u16* __restrict__ Bt,
    const float* __restrict__ bias,
    u16* __restrict__ Oq, u16* __restrict__ Ok, u16* __restrict__ Vt,
    float* __restrict__ Cout)
{
  __shared__ u16 smem[128*136];   // 34,816 B: staging uses [0..16383]; w==2 transpose uses all
  u16* As = smem;
  u16* Bs = smem + 128*64;
  const int n0 = blockIdx.x*128;
  const int m0 = blockIdx.y*128;
  const int w  = blockIdx.z;
  const u16* Bw = Bt + (size_t)w*640*640;
  const int tid = threadIdx.x;
  const int wid = tid>>6, lane = tid&63;
  const int wr = wid>>1, wc = wid&1;
  const int lrow = lane&15, lk = (lane>>4)<<3;

  f32x4 acc[4][4];
  #pragma unroll
  for (int i=0;i<4;++i)
    #pragma unroll
    for (int j=0;j<4;++j) acc[i][j] = (f32x4)0.0f;

  const int srow = wid*32 + (lane>>3);
  const int schunk = (lane&7)*8;

  for (int kt=0; kt<10; ++kt){
    const int k0 = kt*64;
    __syncthreads();
    #pragma unroll
    for (int j=0;j<4;++j){
      const u16* gA = A  + (size_t)(m0 + srow + j*8)*640 + k0 + schunk;
      const u16* gB = Bw + (size_t)(n0 + srow + j*8)*640 + k0 + schunk;
      __builtin_amdgcn_global_load_lds((const __attribute__((address_space(1))) void*)gA,
          (__attribute__((address_space(3))) void*)(As + (wid*32 + j*8)*64), 16, 0, 0);
      __builtin_amdgcn_global_load_lds((const __attribute__((address_space(1))) void*)gB,
          (__attribute__((address_space(3))) void*)(Bs + (wid*32 + j*8)*64), 16, 0, 0);
    }
    __syncthreads();
    #pragma unroll
    for (int kk=0; kk<2; ++kk){
      bf16x8 af[4], bfr[4];
      #pragma unroll
      for (int mi=0;mi<4;++mi)
        af[mi] = *(const bf16x8*)(As + (wr*64 + mi*16 + lrow)*64 + kk*32 + lk);
      #pragma unroll
      for (int ni=0;ni<4;++ni)
        bfr[ni] = *(const bf16x8*)(Bs + (wc*64 + ni*16 + lrow)*64 + kk*32 + lk);
      #pragma unroll
      for (int mi=0;mi<4;++mi)
        #pragma unroll
        for (int ni=0;ni<4;++ni)
          acc[mi][ni] = MFMA16(af[mi], bfr[ni], acc[mi][ni]);
    }
  }

  if (MODE==0){
    if (w < 2){
      int hh4[4], dd4[4];
      #pragma unroll
      for (int ni=0;ni<4;++ni){
        int nn = n0 + wc*64 + ni*16 + lrow;
        hh4[ni] = nn/80; dd4[ni] = nn - hh4[ni]*80;
      }
      u16* dst = (w==0)?Oq:Ok;
      #pragma unroll
      for (int mi=0;mi<4;++mi){
        #pragma unroll
        for (int r=0;r<4;++r){
          int m = m0 + wr*64 + mi*16 + ((lane>>4)<<2) + r;
          int b = m>>10, s = m&1023;
          size_t base0 = ((size_t)b*8192 + (size_t)s)*80;
          #pragma unroll
          for (int ni=0;ni<4;++ni)
            dst[base0 + (size_t)hh4[ni]*81920 + dd4[ni]] = f2bf(acc[mi][ni][r]);
        }
      }
    } else {
      // V^T via LDS transpose: acc -> smem[n_local][m_local] (stride 136, 2-way banks),
      // then coalesced row writes (128B runs along s).
      __syncthreads();   // all K-loop smem reads complete
      #pragma unroll
      for (int mi=0;mi<4;++mi){
        #pragma unroll
        for (int r=0;r<4;++r){
          int ml = wr*64 + mi*16 + ((lane>>4)<<2) + r;
          #pragma unroll
          for (int ni=0;ni<4;++ni){
            int nl = wc*64 + ni*16 + lrow;
            smem[nl*136 + ml] = f2bf(acc[mi][ni][r]);
          }
        }
      }
      __syncthreads();
      // 2 threads per n-row: each writes 64 contiguous u16 (8 x uint4)
      int nl = tid >> 1, mh = (tid & 1) << 6;
      int nn = n0 + nl;
      int h = nn/80, d = nn - h*80;
      int m = m0 + mh;
      int b = m>>10, s = m&1023;
      u16* dst = Vt + ((size_t)(b*8 + h)*80 + d)*1024 + s;
      const u16* src = smem + nl*136 + mh;
      #pragma unroll
      for (int c=0;c<8;++c)
        *(uint4*)(dst + c*8) = *(const uint4*)(src + c*8);
    }
  } else {
    int nn4[4]; float b4[4];
    #pragma unroll
    for (int ni=0;ni<4;++ni){
      nn4[ni] = n0 + wc*64 + ni*16 + lrow;
      b4[ni] = bias[nn4[ni]];
    }
    #pragma unroll
    for (int mi=0;mi<4;++mi){
      #pragma unroll
      for (int r=0;r<4;++r){
        int m = m0 + wr*64 + mi*16 + ((lane>>4)<<2) + r;
        #pragma unroll
        for (int ni=0;ni<4;++ni)
          Cout[(size_t)m*640 + nn4[ni]] = acc[mi][ni][r] + b4[ni];
      }
    }
  }
}

// ---------------- Flash attention v14: v8 core + balanced dual-task grid ----------------
// (unchanged from R16 — 113 µs, verified)
__global__ __launch_bounds__(256,2) void attn_kernel(
    const u16* __restrict__ Q, const u16* __restrict__ K,
    const u16* __restrict__ Vt, u16* __restrict__ O)
{
  __shared__ u16 Ks[2][64*104];   // sigma-permuted rows, cols 80..95 zeroed
  __shared__ u16 Vs[2][80*72];    // V^T tile [d 80][kv 64 + 8 pad]

  const int bx0 = blockIdx.x;
  const int x = bx0 & 7, o = bx0 >> 3;     // o in [0,64)
  const bool combo = (o < 32);
  const int lt = combo ? (x*32 + o) : (256 + x*32 + (o-32));
  const int st = x*32 + o;

  const int tid = threadIdx.x, wid = tid>>6, lane = tid&63;
  const int lrow = lane&15, lk = (lane>>4)<<3;
  const int rbase = (lane>>4)<<2;

  { // zero K pad cols 80..95 in both buffers
    int r = tid>>2, c = 80 + ((tid&3)<<2);
    uint2 z; z.x=0u; z.y=0u;
    *(uint2*)&Ks[0][r*104 + c] = z;
    *(uint2*)&Ks[1][r*104 + c] = z;
  }

  const float SCL = 0.1118033988749895f * 1.4426950408889634f; // 80^-0.5 * log2(e)

  const int c0 = tid, c1 = tid+256, c2 = tid+512;
  const bool has2 = (c2 < 640);
  int kd0, kd1, kd2;
  {
    int cc[3] = {c0,c1,c2};
    int kd[3];
    #pragma unroll
    for (int t=0;t<3;++t){
      int kv = cc[t]/10, dp = cc[t]-kv*10;
      int kb = ((kv>>4)&2)|((kv>>2)&1);
      int ii = ((kv>>1)&0xC)|(kv&3);
      kd[t] = (kb*16+ii)*104 + dp*8;
    }
    kd0 = kd[0]; kd1 = kd[1]; kd2 = kd[2];
  }
  const int vd0 = (c0>>3)*72 + ((c0&7)<<3), vd1 = (c1>>3)*72 + ((c1&7)<<3), vd2 = (c2>>3)*72 + ((c2&7)<<3);
  const int vg0 = (c0>>3)*1024 + ((c0&7)<<3), vg1 = (c1>>3)*1024 + ((c1&7)<<3), vg2 = (c2>>3)*1024 + ((c2&7)<<3);

  uint4 kreg0,kreg1,kreg2, vreg0,vreg1,vreg2;

  #define KVBASE(kt, Kb, Vb) { \
    int fk = (g==0)? (b&3) : ((kt)>>4); \
    int s0 = ((g==0)? (kt) : ((kt)&15))<<6; \
    int bk = g*4 + fk; \
    Kb = K  + ((size_t)((bk*8+hh)*1024 + s0))*80; \
    Vb = Vt + ((size_t)(bk*8+hh))*81920 + s0; }

  #define LOADKV(Kb, Vb) { \
    kreg0 = *(const uint4*)((Kb) + c0*8); \
    kreg1 = *(const uint4*)((Kb) + c1*8); \
    if (has2) kreg2 = *(const uint4*)((Kb) + c2*8); \
    vreg0 = *(const uint4*)((Vb) + vg0); \
    vreg1 = *(const uint4*)((Vb) + vg1); \
    if (has2) vreg2 = *(const uint4*)((Vb) + vg2); }

  #define WRITEKV(buf) { \
    *(uint4*)&Ks[buf][kd0] = kreg0; \
    *(uint4*)&Ks[buf][kd1] = kreg1; \
    if (has2) *(uint4*)&Ks[buf][kd2] = kreg2; \
    *(uint4*)&Vs[buf][vd0] = vreg0; \
    *(uint4*)&Vs[buf][vd1] = vreg1; \
    if (has2) *(uint4*)&Vs[buf][vd2] = vreg2; }

  const int ntasks = combo ? 2 : 1;
  for (int task = 0; task < ntasks; ++task){
    int g, b, hh, qt;
    if (task == 0){
      g = 1 + (lt>>8);
      int r = lt & 255;
      b = g*4 + (r>>6); hh = (r>>3)&7; qt = r&7;
    } else {
      g = 0;
      b = st>>6; hh = (st>>3)&7; qt = st&7;
    }
    const int nkt = (g==0)?16:64;

    const u16* qbase = Q + ((size_t)((b*8+hh)*1024 + qt*128 + wid*32))*80;
    bf16x8 qf[2][3];
    #pragma unroll
    for (int mi=0;mi<2;++mi){
      #pragma unroll
      for (int kk=0;kk<3;++kk){
        int d0 = kk*32 + lk;
        if (d0 < 80){
          bf16x8 raw = *(const bf16x8*)&qbase[(mi*16+lrow)*80 + d0];
          #pragma unroll
          for (int j=0;j<8;++j) qf[mi][kk][j] = (short)f2bf(bf2f((u16)raw[j])*SCL);
        } else {
          #pragma unroll
          for (int j=0;j<8;++j) qf[mi][kk][j] = 0;
        }
      }
    }

    f32x4 o_acc[2][5];
    float l_r[2];
    #pragma unroll
    for (int mi=0;mi<2;++mi){
      #pragma unroll
      for (int db=0;db<5;++db) o_acc[mi][db] = (f32x4)0.0f;
      l_r[mi] = 0.0f;
    }

    { const u16 *Kb; const u16 *Vb; KVBASE(0, Kb, Vb); LOADKV(Kb, Vb); WRITEKV(0); }
    { const u16 *Kb; const u16 *Vb; KVBASE(1, Kb, Vb); LOADKV(Kb, Vb); }
    __syncthreads();

    for (int kt=0; kt<nkt; ++kt){
      const int cur = kt&1;
      const bool more = (kt+1 < nkt);

      f32x4 stv[2][4];
      #pragma unroll
      for (int mi=0;mi<2;++mi)
        #pragma unroll
        for (int kb=0;kb<4;++kb) stv[mi][kb] = (f32x4)0.0f;
      #pragma unroll
      for (int kk=0;kk<3;++kk){
        bf16x8 kf[4];
        #pragma unroll
        for (int kb=0;kb<4;++kb)
          kf[kb] = *(const bf16x8*)&Ks[cur][(kb*16+lrow)*104 + kk*32 + lk];
        __builtin_amdgcn_s_setprio(1);
        #pragma unroll
        for (int mi=0;mi<2;++mi)
          #pragma unroll
          for (int kb=0;kb<4;++kb)
            stv[mi][kb] = MFMA16(kf[kb], qf[mi][kk], stv[mi][kb]);
        __builtin_amdgcn_s_setprio(0);
      }

      bf16x8 vfr[2][5];
      #pragma unroll
      for (int kk=0;kk<2;++kk)
        #pragma unroll
        for (int db=0;db<5;++db)
          vfr[kk][db] = *(const bf16x8*)&Vs[cur][(db*16+lrow)*72 + kk*32 + lk];

      if (more){
        WRITEKV(cur^1);
        if (kt+2 < nkt){ const u16 *Kb; const u16 *Vb; KVBASE(kt+2, Kb, Vb); LOADKV(Kb, Vb); }
        __syncthreads();
      }

      bf16x8 pa[2][2];
      #pragma unroll
      for (int mi=0;mi<2;++mi){
        #pragma unroll
        for (int kb=0;kb<4;++kb)
          #pragma unroll
          for (int r=0;r<4;++r)
            stv[mi][kb][r] = __builtin_amdgcn_exp2f(stv[mi][kb][r]);
        float s0 = (stv[mi][0][0]+stv[mi][0][1]) + (stv[mi][0][2]+stv[mi][0][3]);
        float s1 = (stv[mi][1][0]+stv[mi][1][1]) + (stv[mi][1][2]+stv[mi][1][3]);
        float s2 = (stv[mi][2][0]+stv[mi][2][1]) + (stv[mi][2][2]+stv[mi][2][3]);
        float s3 = (stv[mi][3][0]+stv[mi][3][1]) + (stv[mi][3][2]+stv[mi][3][3]);
        l_r[mi] += (s0+s1) + (s2+s3);
        #pragma unroll
        for (int kk=0;kk<2;++kk){
          u32x4 w;
          w.x = cvt_pk_bf16(stv[mi][2*kk  ][0], stv[mi][2*kk  ][1]);
          w.y = cvt_pk_bf16(stv[mi][2*kk  ][2], stv[mi][2*kk  ][3]);
          w.z = cvt_pk_bf16(stv[mi][2*kk+1][0], stv[mi][2*kk+1][1]);
          w.w = cvt_pk_bf16(stv[mi][2*kk+1][2], stv[mi][2*kk+1][3]);
          pa[mi][kk] = __builtin_bit_cast(bf16x8, w);
        }
      }

      __builtin_amdgcn_s_setprio(1);
      #pragma unroll
      for (int mi=0;mi<2;++mi)
        #pragma unroll
        for (int kk=0;kk<2;++kk)
          #pragma unroll
          for (int db=0;db<5;++db)
            o_acc[mi][db] = MFMA16(pa[mi][kk], vfr[kk][db], o_acc[mi][db]);
      __builtin_amdgcn_s_setprio(0);
    }

    #pragma unroll
    for (int mi=0;mi<2;++mi){
      float lf = l_r[mi];
      lf += __shfl_xor(lf, 16, 64);
      lf += __shfl_xor(lf, 32, 64);
      #pragma unroll
      for (int r=0;r<4;++r){
        float inv = 1.0f / __shfl(lf, (lane & 48) | (rbase + r), 64);
        int s = qt*128 + wid*32 + mi*16 + rbase + r;
        u16* orow = O + ((size_t)(b*1024 + s))*640 + hh*80;
        #pragma unroll
        for (int db=0;db<5;++db)
          orow[db*16 + lrow] = f2bf(o_acc[mi][db][r]*inv);
      }
    }
  }
  #undef KVBASE
  #undef LOADKV
  #undef WRITEKV
}

// ---------------- launch ----------------
extern "C" void kernel_launch(void* const* d_in, const int* in_sizes, int n_in,
                              void* d_out, int out_size, void* d_ws, size_t ws_size,
                              hipStream_t stream)
{
  const float* x  = (const float*)d_in[0];
  const float* Wq = (const float*)d_in[1];
  const float* Wk = (const float*)d_in[2];
  const float* Wv = (const float*)d_in[3];
  const float* Wo = (const float*)d_in[4];
  const float* bo = (const float*)d_in[5];
  float* out = (float*)d_out;

  char* ws = (char*)d_ws;
  u16* xbf = (u16*)(ws);
  u16* wt  = (u16*)(ws + 15728640);
  u16* wot = (u16*)(ws + 18186240);
  u16* Qw  = (u16*)(ws + 19005440);
  u16* Kw  = (u16*)(ws + 34734080);
  u16* Vtw = (u16*)(ws + 50462720);
  u16* Ow  = (u16*)(ws + 66191360);

  cvt_x_kernel<<<7680, 256, 0, stream>>>(x, xbf);
  cvt_w_kernel<<<dim3(20,20,4), dim3(32,8,1), 0, stream>>>(Wq,Wk,Wv,Wo, wt, wot);
  gemm_kernel<0><<<dim3(5,96,3), 256, 0, stream>>>(xbf, wt, nullptr, Qw, Kw, Vtw, nullptr);
  attn_kernel<<<512, 256, 0, stream>>>(Qw, Kw, Vtw, Ow);
  gemm_kernel<1><<<dim3(5,96,1), 256, 0, stream>>>(Ow, wot, bo, nullptr, nullptr, nullptr, out);
}